// Round 1
// baseline (501.565 us; speedup 1.0000x reference)
//
#include <hip/hip_runtime.h>

#define N_NODES 8192
#define N_EDGES 131072
#define NGRAPH  64
#define DIM     32
#define HID     128
#define SROW    34   // padded S row stride (floats): breaks 32-bank alignment, keeps 8B align

__device__ __forceinline__ float sigmoidf_(float x) { return 1.0f / (1.0f + expf(-x)); }

// ---------------- prep kernels ----------------
__global__ void init_nodes_kernel(const float* __restrict__ x,
                                  const float* __restrict__ w,
                                  const float* __restrict__ b,
                                  float* __restrict__ out) {
  int idx = blockIdx.x * 256 + threadIdx.x;
  if (idx >= N_NODES * DIM) return;
  int n = idx >> 5, d = idx & 31;
  out[idx] = fmaxf(fmaf(x[n], w[d], b[d]), 0.0f);
}

__global__ void hist_kernel(const int* __restrict__ dst, int* __restrict__ counts) {
  int e = blockIdx.x * 256 + threadIdx.x;
  if (e < N_EDGES) atomicAdd(&counts[dst[e]], 1);
}

__global__ void scan_kernel(const int* __restrict__ counts,
                            int* __restrict__ offsets,
                            float* __restrict__ deg_inv) {
  __shared__ int sm[1024];
  int t = threadIdx.x;
  int base = t * 8;
  int loc[8];
  int s = 0;
#pragma unroll
  for (int i = 0; i < 8; ++i) { loc[i] = s; s += counts[base + i]; }
  sm[t] = s;
  __syncthreads();
  for (int off = 1; off < 1024; off <<= 1) {
    int v = (t >= off) ? sm[t - off] : 0;
    __syncthreads();
    sm[t] += v;
    __syncthreads();
  }
  int excl = (t > 0) ? sm[t - 1] : 0;
#pragma unroll
  for (int i = 0; i < 8; ++i) {
    offsets[base + i] = excl + loc[i];
    int c = counts[base + i];
    deg_inv[base + i] = 1.0f / (float)(c > 0 ? c : 1);
  }
  if (t == 1023) offsets[N_NODES] = sm[1023];
}

__global__ void scatter_kernel(const int* __restrict__ ei,
                               const float* __restrict__ ea,
                               const int* __restrict__ offsets,
                               int* __restrict__ cursor,
                               int* __restrict__ csr_src,
                               float2* __restrict__ csr_ea) {
  int e = blockIdx.x * 256 + threadIdx.x;
  if (e >= N_EDGES) return;
  int d = ei[N_EDGES + e];
  int pos = atomicAdd(&cursor[d], 1);
  int slot = offsets[d] + pos;
  csr_src[slot] = ei[e];
  csr_ea[slot] = make_float2(ea[2 * e], ea[2 * e + 1]);
}

__global__ void gstart_kernel(const int* __restrict__ batch, int* __restrict__ gstart) {
  int n = blockIdx.x * 256 + threadIdx.x;
  if (n >= N_NODES) return;
  int b = batch[n];
  if (n == 0) {
    for (int g = 0; g <= b; ++g) gstart[g] = 0;
  } else {
    int bp = batch[n - 1];
    for (int g = bp + 1; g <= b; ++g) gstart[g] = n;
  }
  if (n == N_NODES - 1) {
    for (int g = b + 1; g <= NGRAPH; ++g) gstart[g] = N_NODES;
  }
}

// ---------------- fused MP layer ----------------
// Per block: G nodes. Build S[g][k][d] = sum_{e->g} hid[e,k]*out[src,d] in regs->LDS,
// O[g][d] = sum out[src,d]; contract with w2; add O*b2 bias term; scale by 1/deg;
// then fused root-linear + GRU cell epilogue.
template <int G, int C>
__global__ __launch_bounds__(256) void mp_kernel(
    const float* __restrict__ out_cur, float* __restrict__ out_nxt,
    const int* __restrict__ offsets, const float* __restrict__ deg_inv,
    const int* __restrict__ csr_src, const float2* __restrict__ csr_ea,
    const float* __restrict__ w1, const float* __restrict__ b1,
    const float* __restrict__ w2, const float* __restrict__ b2,
    const float* __restrict__ root_w, const float* __restrict__ conv_b,
    const float* __restrict__ gwih, const float* __restrict__ gwhh,
    const float* __restrict__ gbih, const float* __restrict__ gbhh) {
  __shared__ float S[G * HID * SROW];   // also reused as reduction scratch
  __shared__ float hidb[C * HID];
  __shared__ float osrcb[C * DIM];
  __shared__ float Ob[G * DIM];
  __shared__ float aggb[G * DIM];
  __shared__ float mb[G * DIM];
  __shared__ float hb[G * DIM];
  __shared__ int offs[G + 1];
  __shared__ float dinvb[G];

  const int t = threadIdx.x;
  const int node0 = blockIdx.x * G;

  if (t <= G) offs[t] = offsets[min(node0 + t, N_NODES)];
  if (t < G) dinvb[t] = deg_inv[min(node0 + t, N_NODES - 1)];

  // build-phase tile: thread owns k in [k0,k0+4), d in [d0,d0+4)
  const int kg = t >> 3, dg = t & 7;
  const int k0 = kg * 4, d0 = dg * 4;
  // staging: thread handles edge ec, sub-slice sub
  const int ec = t / (256 / C);
  const int sub = t % (256 / C);
  __syncthreads();

  for (int g = 0; g < G; ++g) {
    float acc[4][4];
#pragma unroll
    for (int i = 0; i < 4; ++i)
#pragma unroll
      for (int j = 0; j < 4; ++j) acc[i][j] = 0.0f;
    float oacc = 0.0f;
    const int base = offs[g], end = offs[g + 1];
    for (int c0 = base; c0 < end; c0 += C) {
      const int cnt = min(C, end - c0);
      __syncthreads();  // protect hidb/osrcb from previous readers
      if (ec < cnt) {
        const int slot = c0 + ec;
        const float2 eav = csr_ea[slot];
        const int sidx = csr_src[slot];
        // hid slice: 128/(256/C) values per thread (C=16 -> 8)
#pragma unroll
        for (int i = 0; i < HID / (256 / C); ++i) {
          const int k = sub * (HID / (256 / C)) + i;
          float v = fmaf(eav.y, w1[HID + k], fmaf(eav.x, w1[k], b1[k]));
          hidb[ec * HID + k] = fmaxf(v, 0.0f);
        }
        // out[src] slice: 32/(256/C) values (C=16 -> 2)
        const float2 ov = *(const float2*)(out_cur + sidx * DIM + sub * 2);
        *(float2*)(osrcb + ec * DIM + sub * 2) = ov;
      }
      __syncthreads();
      for (int e = 0; e < cnt; ++e) {
        const float4 hv = *(const float4*)(hidb + e * HID + k0);
        const float4 ov = *(const float4*)(osrcb + e * DIM + d0);
        acc[0][0] = fmaf(hv.x, ov.x, acc[0][0]);
        acc[0][1] = fmaf(hv.x, ov.y, acc[0][1]);
        acc[0][2] = fmaf(hv.x, ov.z, acc[0][2]);
        acc[0][3] = fmaf(hv.x, ov.w, acc[0][3]);
        acc[1][0] = fmaf(hv.y, ov.x, acc[1][0]);
        acc[1][1] = fmaf(hv.y, ov.y, acc[1][1]);
        acc[1][2] = fmaf(hv.y, ov.z, acc[1][2]);
        acc[1][3] = fmaf(hv.y, ov.w, acc[1][3]);
        acc[2][0] = fmaf(hv.z, ov.x, acc[2][0]);
        acc[2][1] = fmaf(hv.z, ov.y, acc[2][1]);
        acc[2][2] = fmaf(hv.z, ov.z, acc[2][2]);
        acc[2][3] = fmaf(hv.z, ov.w, acc[2][3]);
        acc[3][0] = fmaf(hv.w, ov.x, acc[3][0]);
        acc[3][1] = fmaf(hv.w, ov.y, acc[3][1]);
        acc[3][2] = fmaf(hv.w, ov.z, acc[3][2]);
        acc[3][3] = fmaf(hv.w, ov.w, acc[3][3]);
        if (t < DIM) oacc += osrcb[e * DIM + t];
      }
    }
    // dump S tile (b64 writes, 8B aligned since SROW even and d0 even)
    float* Sg = S + g * HID * SROW;
#pragma unroll
    for (int i = 0; i < 4; ++i) {
      *(float2*)(Sg + (k0 + i) * SROW + d0) = make_float2(acc[i][0], acc[i][1]);
      *(float2*)(Sg + (k0 + i) * SROW + d0 + 2) = make_float2(acc[i][2], acc[i][3]);
    }
    if (t < DIM) Ob[g * DIM + t] = oacc;
  }
  __syncthreads();

  // contraction: thread (ks = t>>3 in 0..31, og = t&7); k in [ks*4, ks*4+4)
  {
    const int ks = t >> 3, og = t & 7;
    const int o0 = og * 4;
    float a4[G][4];
#pragma unroll
    for (int g = 0; g < G; ++g)
#pragma unroll
      for (int j = 0; j < 4; ++j) a4[g][j] = 0.0f;
#pragma unroll
    for (int i = 0; i < 4; ++i) {
      const int k = ks * 4 + i;
      const float* w2k = w2 + k * (DIM * DIM);
#pragma unroll
      for (int dv = 0; dv < 8; ++dv) {
        const float4 wq0 = *(const float4*)(w2k + (dv * 4 + 0) * DIM + o0);
        const float4 wq1 = *(const float4*)(w2k + (dv * 4 + 1) * DIM + o0);
        const float4 wq2 = *(const float4*)(w2k + (dv * 4 + 2) * DIM + o0);
        const float4 wq3 = *(const float4*)(w2k + (dv * 4 + 3) * DIM + o0);
#pragma unroll
        for (int g = 0; g < G; ++g) {
          const float* Srow = S + g * HID * SROW + k * SROW + dv * 4;
          const float2 sa = *(const float2*)(Srow);
          const float2 sb = *(const float2*)(Srow + 2);
          a4[g][0] = fmaf(sa.x, wq0.x, fmaf(sa.y, wq1.x, fmaf(sb.x, wq2.x, fmaf(sb.y, wq3.x, a4[g][0]))));
          a4[g][1] = fmaf(sa.x, wq0.y, fmaf(sa.y, wq1.y, fmaf(sb.x, wq2.y, fmaf(sb.y, wq3.y, a4[g][1]))));
          a4[g][2] = fmaf(sa.x, wq0.z, fmaf(sa.y, wq1.z, fmaf(sb.x, wq2.z, fmaf(sb.y, wq3.z, a4[g][2]))));
          a4[g][3] = fmaf(sa.x, wq0.w, fmaf(sa.y, wq1.w, fmaf(sb.x, wq2.w, fmaf(sb.y, wq3.w, a4[g][3]))));
        }
      }
    }
    __syncthreads();  // S reads done; reuse S as reduction scratch
#pragma unroll
    for (int g = 0; g < G; ++g)
#pragma unroll
      for (int j = 0; j < 4; ++j) S[(g * 4 + j) * 256 + t] = a4[g][j];
  }
  __syncthreads();

  // reduce over ks, add O*b2 bias term, scale by 1/deg
  if (t < G * DIM) {
    const int g = t >> 5, o = t & 31;
    const int og = o >> 2, j = o & 3;
    float sum = 0.0f;
    for (int ks = 0; ks < 32; ++ks) sum += S[(g * 4 + j) * 256 + ks * 8 + og];
    float ob = 0.0f;
#pragma unroll
    for (int d = 0; d < DIM; ++d) ob = fmaf(Ob[g * DIM + d], b2[d * DIM + o], ob);
    aggb[t] = (sum + ob) * dinvb[g];
  }
  // stage h (= current out) rows
  if (t < G * DIM) {
    const int g = t >> 5, o = t & 31;
    const int node = node0 + g;
    hb[t] = (node < N_NODES) ? out_cur[node * DIM + o] : 0.0f;
  }
  __syncthreads();
  // m = relu(agg + h @ root_w + conv_b)
  if (t < G * DIM) {
    const int g = t >> 5, o = t & 31;
    float rt = conv_b[o];
#pragma unroll
    for (int d = 0; d < DIM; ++d) rt = fmaf(hb[g * DIM + d], root_w[d * DIM + o], rt);
    mb[t] = fmaxf(aggb[t] + rt, 0.0f);
  }
  __syncthreads();
  // GRU cell
  if (t < G * DIM) {
    const int g = t >> 5, o = t & 31;
    const int node = node0 + g;
    if (node < N_NODES) {
      float gi[3], gh[3];
#pragma unroll
      for (int jj = 0; jj < 3; ++jj) {
        float si = gbih[jj * DIM + o], sh = gbhh[jj * DIM + o];
#pragma unroll
        for (int d = 0; d < DIM; ++d) {
          si = fmaf(mb[g * DIM + d], gwih[d * 3 * DIM + jj * DIM + o], si);
          sh = fmaf(hb[g * DIM + d], gwhh[d * 3 * DIM + jj * DIM + o], sh);
        }
        gi[jj] = si;
        gh[jj] = sh;
      }
      const float r = sigmoidf_(gi[0] + gh[0]);
      const float z = sigmoidf_(gi[1] + gh[1]);
      const float nn = tanhf(fmaf(r, gh[2], gi[2]));
      out_nxt[node * DIM + o] = (1.0f - z) * nn + z * hb[t];
    }
  }
}

// ---------------- Set2Set + head: one block per graph ----------------
__global__ __launch_bounds__(256) void s2s_kernel(
    const float* __restrict__ outf, const int* __restrict__ gstart,
    const float* __restrict__ wih, const float* __restrict__ whh,
    const float* __restrict__ bih, const float* __restrict__ bhh,
    const float* __restrict__ l1w, const float* __restrict__ l1b,
    const float* __restrict__ l2w, const float* __restrict__ l2b,
    float* __restrict__ y) {
  __shared__ float qh[DIM], qc[DIM], qstar[2 * DIM], gates[4 * DIM];
  __shared__ float wsum[4], wmax[4], wr[4][DIM];
  const int b = blockIdx.x, t = threadIdx.x;
  const int gs = gstart[b], ge = gstart[b + 1];
  const int w = t >> 6, lane = t & 63;
  if (t < DIM) { qh[t] = 0.0f; qc[t] = 0.0f; }
  if (t < 2 * DIM) qstar[t] = 0.0f;
  __syncthreads();
  for (int step = 0; step < 3; ++step) {
    // LSTM cell
    if (t < 4 * DIM) {
      float gv = bih[t] + bhh[t];
      for (int i = 0; i < 2 * DIM; ++i) gv = fmaf(qstar[i], wih[i * 4 * DIM + t], gv);
      for (int i = 0; i < DIM; ++i) gv = fmaf(qh[i], whh[i * 4 * DIM + t], gv);
      gates[t] = gv;
    }
    __syncthreads();
    if (t < DIM) {
      const float ig = sigmoidf_(gates[t]);
      const float fg = sigmoidf_(gates[DIM + t]);
      const float gg = tanhf(gates[2 * DIM + t]);
      const float og = sigmoidf_(gates[3 * DIM + t]);
      const float c = fmaf(fg, qc[t], ig * gg);
      qc[t] = c;
      qh[t] = og * tanhf(c);
    }
    __syncthreads();
    // attention pass 1: logits max
    float lmax = -INFINITY;
    for (int n = gs + t; n < ge; n += 256) {
      const float* orow = outf + n * DIM;
      float e = 0.0f;
#pragma unroll
      for (int d = 0; d < DIM; ++d) e = fmaf(orow[d], qh[d], e);
      lmax = fmaxf(lmax, e);
    }
#pragma unroll
    for (int off = 32; off > 0; off >>= 1) lmax = fmaxf(lmax, __shfl_xor(lmax, off));
    if (lane == 0) wmax[w] = lmax;
    __syncthreads();
    const float gmax = fmaxf(fmaxf(wmax[0], wmax[1]), fmaxf(wmax[2], wmax[3]));
    // pass 2: exp-weights + weighted read
    float rl[DIM];
#pragma unroll
    for (int d = 0; d < DIM; ++d) rl[d] = 0.0f;
    float lsum = 0.0f;
    for (int n = gs + t; n < ge; n += 256) {
      const float* orow = outf + n * DIM;
      float e = 0.0f;
#pragma unroll
      for (int d = 0; d < DIM; ++d) e = fmaf(orow[d], qh[d], e);
      const float a = expf(e - gmax);
      lsum += a;
#pragma unroll
      for (int d = 0; d < DIM; ++d) rl[d] = fmaf(a, orow[d], rl[d]);
    }
#pragma unroll
    for (int off = 32; off > 0; off >>= 1) {
      lsum += __shfl_xor(lsum, off);
#pragma unroll
      for (int d = 0; d < DIM; ++d) rl[d] += __shfl_xor(rl[d], off);
    }
    __syncthreads();
    if (lane == 0) {
      wsum[w] = lsum;
#pragma unroll
      for (int d = 0; d < DIM; ++d) wr[w][d] = rl[d];
    }
    __syncthreads();
    if (t < DIM) {
      const float stot = wsum[0] + wsum[1] + wsum[2] + wsum[3];
      const float rv = wr[0][t] + wr[1][t] + wr[2][t] + wr[3][t];
      qstar[t] = qh[t];
      qstar[DIM + t] = (stot > 0.0f) ? rv / stot : 0.0f;
    }
    __syncthreads();
  }
  // head: y = relu(qstar@l1w + l1b) @ l2w + l2b
  if (t < DIM) {
    float u = l1b[t];
    for (int i = 0; i < 2 * DIM; ++i) u = fmaf(qstar[i], l1w[i * DIM + t], u);
    u = fmaxf(u, 0.0f);
    float v = u * l2w[t];
#pragma unroll
    for (int off = 16; off > 0; off >>= 1) v += __shfl_xor(v, off);
    if (t == 0) y[b] = v + l2b[0];
  }
}

extern "C" void kernel_launch(void* const* d_in, const int* in_sizes, int n_in,
                              void* d_out, int out_size, void* d_ws, size_t ws_size,
                              hipStream_t stream) {
  const float* x        = (const float*)d_in[0];
  const float* ea       = (const float*)d_in[1];
  const float* lin0_w   = (const float*)d_in[2];
  const float* lin0_b   = (const float*)d_in[3];
  const float* enn_w1   = (const float*)d_in[4];
  const float* enn_b1   = (const float*)d_in[5];
  const float* enn_w2   = (const float*)d_in[6];
  const float* enn_b2   = (const float*)d_in[7];
  const float* root_w   = (const float*)d_in[8];
  const float* conv_b   = (const float*)d_in[9];
  const float* gru_wih  = (const float*)d_in[10];
  const float* gru_whh  = (const float*)d_in[11];
  const float* gru_bih  = (const float*)d_in[12];
  const float* gru_bhh  = (const float*)d_in[13];
  const float* s2s_wih  = (const float*)d_in[14];
  const float* s2s_whh  = (const float*)d_in[15];
  const float* s2s_bih  = (const float*)d_in[16];
  const float* s2s_bhh  = (const float*)d_in[17];
  const float* lin1_w   = (const float*)d_in[18];
  const float* lin1_b   = (const float*)d_in[19];
  const float* lin2_w   = (const float*)d_in[20];
  const float* lin2_b   = (const float*)d_in[21];
  const int*   ei       = (const int*)d_in[22];
  const int*   batch    = (const int*)d_in[23];
  float* y = (float*)d_out;

  // workspace bump allocator (256B aligned)
  char* p = (char*)d_ws;
  auto alloc = [&](size_t bytes) -> void* {
    void* r = (void*)p;
    p += (bytes + 255) & ~(size_t)255;
    return r;
  };
  float*  out_a   = (float*)alloc(N_NODES * DIM * 4);
  float*  out_b   = (float*)alloc(N_NODES * DIM * 4);
  int*    counts  = (int*)alloc(N_NODES * 4);
  int*    offsets = (int*)alloc((N_NODES + 1) * 4);
  int*    cursor  = (int*)alloc(N_NODES * 4);
  int*    csr_src = (int*)alloc(N_EDGES * 4);
  float2* csr_ea  = (float2*)alloc(N_EDGES * 8);
  float*  deg_inv = (float*)alloc(N_NODES * 4);
  int*    gstart  = (int*)alloc((NGRAPH + 1) * 4);
  (void)ws_size; (void)n_in; (void)in_sizes; (void)out_size;

  hipMemsetAsync(counts, 0, N_NODES * 4, stream);
  hipMemsetAsync(cursor, 0, N_NODES * 4, stream);

  init_nodes_kernel<<<(N_NODES * DIM) / 256, 256, 0, stream>>>(x, lin0_w, lin0_b, out_a);
  hist_kernel<<<N_EDGES / 256, 256, 0, stream>>>(ei + N_EDGES, counts);
  scan_kernel<<<1, 1024, 0, stream>>>(counts, offsets, deg_inv);
  scatter_kernel<<<N_EDGES / 256, 256, 0, stream>>>(ei, ea, offsets, cursor, csr_src, csr_ea);
  gstart_kernel<<<N_NODES / 256, 256, 0, stream>>>(batch, gstart);

  constexpr int G = 3, C = 16;
  const int mp_blocks = (N_NODES + G - 1) / G;
  mp_kernel<G, C><<<mp_blocks, 256, 0, stream>>>(
      out_a, out_b, offsets, deg_inv, csr_src, csr_ea, enn_w1, enn_b1, enn_w2, enn_b2,
      root_w, conv_b, gru_wih, gru_whh, gru_bih, gru_bhh);
  mp_kernel<G, C><<<mp_blocks, 256, 0, stream>>>(
      out_b, out_a, offsets, deg_inv, csr_src, csr_ea, enn_w1, enn_b1, enn_w2, enn_b2,
      root_w, conv_b, gru_wih, gru_whh, gru_bih, gru_bhh);
  mp_kernel<G, C><<<mp_blocks, 256, 0, stream>>>(
      out_a, out_b, offsets, deg_inv, csr_src, csr_ea, enn_w1, enn_b1, enn_w2, enn_b2,
      root_w, conv_b, gru_wih, gru_whh, gru_bih, gru_bhh);

  s2s_kernel<<<NGRAPH, 256, 0, stream>>>(out_b, gstart, s2s_wih, s2s_whh, s2s_bih, s2s_bhh,
                                         lin1_w, lin1_b, lin2_w, lin2_b, y);
}